// Round 5
// baseline (167.225 us; speedup 1.0000x reference)
//
#include <hip/hip_runtime.h>
#include <math.h>

#define BISECT_ITERS 60
#define N_ROWS 131072
#define N_PAIRS (2 * N_ROWS)
#define MAX_ITEMS (2 * N_PAIRS)

// float-rounded versions of python doubles (match numpy scalar->f32 cast)
#define E_CONST 2.71828182845904523536f       // float(np.e)
#define SMALL_THRESH 5.65685424949238019520f  // 4*sqrt(2)
#define LN2F 0.69314718055994530942f

// ---------------------------------------------------------------------------
// Correctly-rounded fp32 natural log (double atanh-series, round once).
// Decision-point path — gave absmax 0.0 vs numpy in round 3. Do not touch.
// ---------------------------------------------------------------------------
__device__ __forceinline__ float log_cr(float wc) {
    double d = (double)wc;
    long long b = __double_as_longlong(d);
    int e = (int)((b >> 52) & 0x7FF) - 1023;
    double m = __longlong_as_double((b & 0x000FFFFFFFFFFFFFLL) |
                                    0x3FF0000000000000LL);  // m in [1,2)
    if (m > 1.3333333333333333) {
        m *= 0.5;
        e += 1;
    }
    double s = (m - 1.0) / (m + 1.0);
    double s2 = s * s;
    double p = 1.0 / 17.0;
    p = fma(p, s2, 1.0 / 15.0);
    p = fma(p, s2, 1.0 / 13.0);
    p = fma(p, s2, 1.0 / 11.0);
    p = fma(p, s2, 1.0 / 9.0);
    p = fma(p, s2, 1.0 / 7.0);
    p = fma(p, s2, 1.0 / 5.0);
    p = fma(p, s2, 1.0 / 3.0);
    p = fma(p, s2, 1.0);
    double res = fma(2.0 * s, p, (double)e * 0.69314718055994530941723212145818);
    return (float)res;
}

__device__ __forceinline__ float safe_log_f(float w) {
    return log_cr(fmaxf(w, 1e-12f));
}

__device__ __forceinline__ float clip1f(float x) {
#pragma clang fp contract(off)
    return fminf(fmaxf(x, -1.0f), 1.0f);
}

__device__ __forceinline__ float sl1(float x) {  // smooth_l1, beta=1
#pragma clang fp contract(off)
    float d = fabsf(x);
    return (d < 1.0f) ? (0.5f * d) * d : d - 0.5f;
}

__device__ __forceinline__ float eps_f(float w, float wh, float lwp) {
#pragma clang fp contract(off)
    return sl1((w - wh) * 0.5f) + sl1(safe_log_f(w) - lwp);
}

__device__ __forceinline__ float eps_prime_cr(float w, float wh, float lwp) {
#pragma clang fp contract(off)
    float x = (w - wh) * 0.5f;
    float diff = safe_log_f(w) - lwp;
    return 0.5f * clip1f(x) + clip1f(diff) / fmaxf(w, 1e-12f);
}

__device__ __forceinline__ float sigma_cr(float w, float wh, float lwp) {
#pragma clang fp contract(off)
    return w * eps_prime_cr(w, wh, lwp);
}

// Fast inner-loop sign of eps_prime (multiplied through by max(m,1e-12)>0).
__device__ __forceinline__ float epsp_sign(float m, float wh, float lwp) {
    float wm = fmaxf(m, 1e-12f);
    float x = (m - wh) * 0.5f;
    float diff = __builtin_fmaf(LN2F, __builtin_amdgcn_logf(wm), -lwp);
    return __builtin_fmaf(0.5f * clip1f(x), wm, clip1f(diff));
}

// ---------- _find_min with f = eps_prime (A-path; round-4 verified) ----------
__device__ float find_min_e(float u, float v, float wh, float lwp) {
#pragma clang fp contract(off)
    float u0 = u, v0 = v;
#pragma unroll 1
    for (int i = 0; i < BISECT_ITERS; ++i) {
        float m = (u + v) * 0.5f;
        bool frozen = (m == u) || (m == v);
        bool c = epsp_sign(m, wh, lwp) >= 0.0f;
        u = c ? u : m;
        v = c ? m : v;
        if (__all(frozen)) break;
    }
    float m = (u + v) * 0.5f;
    float r = m;
    if (eps_prime_cr(v0, wh, lwp) <= 0.0f) r = v0;
    if (eps_prime_cr(u0, wh, lwp) >= 0.0f) r = u0;
    return r;
}

// ---------------------------------------------------------------------------
// Per-pair parameters, bit-identical across K1/K2/K3 (fp32 IEEE, contract off)
// ---------------------------------------------------------------------------
struct PairP {
    float pd, po, td, to, a1r, b1r, a1l, b1l;
    int lt, rb;
};

__device__ __forceinline__ PairP load_pair(const float* __restrict__ pred,
                                           const float* __restrict__ target,
                                           const float* __restrict__ crop,
                                           const float* __restrict__ prop,
                                           const int* __restrict__ cases,
                                           int pair) {
#pragma clang fp contract(off)
    int row = pair >> 1, axis = pair & 1;
    int d_id = axis, o_id = axis + 2, r4 = row * 4;
    PairP P;
    P.pd = pred[r4 + d_id];
    P.po = (float)exp((double)pred[r4 + o_id]);
    P.td = target[r4 + d_id];
    P.to = (float)exp((double)target[r4 + o_id]);
    float p_d = prop[r4 + d_id];
    float p_o = prop[r4 + o_id];
    float ca = 0.5f * (p_d + p_o);
    float da = p_o - p_d;
    float crop_a = crop[r4 + axis];
    P.a1r = P.td - 0.5f * P.to;
    P.b1r = (crop_a - ca) / da;
    P.a1l = (-ca) / da;
    P.b1l = P.td + 0.5f * P.to;
    P.lt = cases[r4 + 2 * axis];
    P.rb = cases[r4 + 2 * axis + 1];
    return P;
}

__device__ __forceinline__ void item_params(const PairP& P, int slot,
                                            float& wp, float& wh, float& w0) {
#pragma clang fp contract(off)
    bool need_b = P.lt && P.rb;
    bool need_l = P.lt && !P.rb;
    if (need_b) {
        wp = P.pd;
        wh = (slot == 0) ? 2.0f * (P.pd - P.a1l) : 2.0f * (P.b1r - P.pd);
        w0 = P.b1r - P.a1l;
    } else if (need_l) {
        wp = P.po;
        wh = 2.0f * (P.b1l - P.pd);
        w0 = P.b1l - P.a1l;
    } else {  // r
        wp = P.po;
        wh = 2.0f * (P.pd - P.a1r);
        w0 = P.b1r - P.a1r;
    }
}

// ---------------------------------------------------------------------------
// Full branchB solve: the 5 bisections (c2..c6) FUSED into one loop (5-way
// ILP). Per-iteration updates are idempotent once a sub-interval freezes
// (m==u: c true -> v=u then fixed; c false -> unchanged forever), so running
// all to the max freeze count reproduces each loop's iteration-60 state
// bit-exactly. Endpoint overrides + evals + argmin use the cr path (round-3
// verified decisions).
// ---------------------------------------------------------------------------
__device__ float solve_B(float wp, float wh, float w0, float lwp) {
#pragma clang fp contract(off)
    float ewp = E_CONST * wp;
    float base = fmaxf(w0, fmaxf(wh - 2.0f, ewp));
    float disc = sqrtf(fmaxf(1.0f - 32.0f / fmaxf(wh * wh, 1e-12f), 0.0f));

    float u2 = fmaxf(w0, wp), v2 = fminf(ewp, wh);
    float u3 = fmaxf(fmaxf(w0, 2.0f), fmaxf(wh - 2.0f, ewp)), v3 = wh;
    float u4 = base, v4 = fminf(E_CONST, wh);
    float u5 = base, v5 = fminf(fminf(ewp, wh), (wh * 0.25f) * (1.0f + disc));
    float u6 = fmaxf(base, (wh * 0.25f) * (1.0f - disc)), v6 = fminf(ewp, wh);
    float u02 = u2, v02 = v2, u03 = u3, v03 = v3, u04 = u4, v04 = v4;
    float u05 = u5, v05 = v5, u06 = u6, v06 = v6;

#pragma unroll 1
    for (int i = 0; i < BISECT_ITERS; ++i) {
        float m2 = (u2 + v2) * 0.5f;
        float m3 = (u3 + v3) * 0.5f;
        float m4 = (u4 + v4) * 0.5f;
        float m5 = (u5 + v5) * 0.5f;
        float m6 = (u6 + v6) * 0.5f;
        bool fr = (m2 == u2 || m2 == v2) && (m3 == u3 || m3 == v3) &&
                  (m4 == u4 || m4 == v4) && (m5 == u5 || m5 == v5) &&
                  (m6 == u6 || m6 == v6);
        bool c2 = epsp_sign(m2, wh, lwp) >= 0.0f;
        bool c3 = epsp_sign(m3, wh, lwp) >= 0.0f;
        bool c4 = (m4 * epsp_sign(m4, wh, lwp)) >= 0.0f;
        bool c5 = (m5 * epsp_sign(m5, wh, lwp)) >= 0.0f;
        bool c6 = (m6 * epsp_sign(m6, wh, lwp)) >= 0.0f;
        u2 = c2 ? u2 : m2; v2 = c2 ? m2 : v2;
        u3 = c3 ? u3 : m3; v3 = c3 ? m3 : v3;
        u4 = c4 ? u4 : m4; v4 = c4 ? m4 : v4;
        u5 = c5 ? u5 : m5; v5 = c5 ? m5 : v5;
        u6 = c6 ? u6 : m6; v6 = c6 ? m6 : v6;
        if (__all(fr)) break;
    }

    float c2r = (u2 + v2) * 0.5f;
    if (eps_prime_cr(v02, wh, lwp) <= 0.0f) c2r = v02;
    if (eps_prime_cr(u02, wh, lwp) >= 0.0f) c2r = u02;
    float c3r = (u3 + v3) * 0.5f;
    if (eps_prime_cr(v03, wh, lwp) <= 0.0f) c3r = v03;
    if (eps_prime_cr(u03, wh, lwp) >= 0.0f) c3r = u03;
    float c4r = (u4 + v4) * 0.5f;
    if (sigma_cr(v04, wh, lwp) <= 0.0f) c4r = v04;
    if (sigma_cr(u04, wh, lwp) >= 0.0f) c4r = u04;
    float c5r = (u5 + v5) * 0.5f;
    if (sigma_cr(v05, wh, lwp) <= 0.0f) c5r = v05;
    if (sigma_cr(u05, wh, lwp) >= 0.0f) c5r = u05;
    float c6r = (u6 + v6) * 0.5f;
    if (sigma_cr(v06, wh, lwp) <= 0.0f) c6r = v06;
    if (sigma_cr(u06, wh, lwp) >= 0.0f) c6r = u06;

    bool small_ = wh <= SMALL_THRESH;
    float cands[7] = {w0, wh, c2r, c3r, c4r, c5r, c6r};
    float evals[7];
    evals[0] = eps_f(w0, wh, lwp);
    evals[1] = eps_f(wh, wh, lwp);
    evals[2] = eps_f(c2r, wh, lwp);
    evals[3] = eps_f(c3r, wh, lwp);
    evals[4] = (!small_) ? 1e30f : eps_f(c4r, wh, lwp);
    evals[5] = small_ ? 1e30f : eps_f(c5r, wh, lwp);
    evals[6] = small_ ? 1e30f : eps_f(c6r, wh, lwp);

    float bestv = evals[0];
    float wB = cands[0];
#pragma unroll
    for (int j = 1; j < 7; ++j) {
        if (evals[j] < bestv) {
            bestv = evals[j];
            wB = cands[j];
        }
    }
    return wB;
}

// ---------------------------------------------------------------------------
// Kernel 1: classify every potential solve item with the reference's own
// fp32 predicates; enqueue only items whose result is actually used AND
// requires bisection. Two-ended queue: branchB (full) from bottom,
// branchA (single find_min_e) from top.
// ---------------------------------------------------------------------------
__global__ __launch_bounds__(256)
void classify_kernel(const float* __restrict__ pred,
                     const float* __restrict__ target,
                     const float* __restrict__ crop,
                     const float* __restrict__ prop,
                     const int* __restrict__ cases,
                     int* __restrict__ counters,
                     int* __restrict__ queue) {
#pragma clang fp contract(off)
    int pair = blockIdx.x * blockDim.x + threadIdx.x;
    int nB = 0, nA = 0;
    int bdest[2] = {0, 0}, adest[2] = {0, 0};
    if (pair < N_PAIRS) {
        PairP P = load_pair(pred, target, crop, prop, cases, pair);
        bool need_b = P.lt && P.rb;
        bool need_any = P.lt || P.rb;
        if (need_any) {
            bool skip_all = false;
            if (need_b) {
                float wh1 = 2.0f * (P.pd - P.a1l);
                float wh2 = 2.0f * (P.b1r - P.pd);
                skip_all = P.pd >= fmaxf(wh1, wh2);  // trivial
            }
            if (!skip_all) {
                int nslots = need_b ? 2 : 1;
                for (int s = 0; s < nslots; ++s) {
                    float wp, wh, w0;
                    item_params(P, s, wp, wh, w0);
                    bool bA = fmaxf(w0, wh) < wp;
                    bool bB = fmaxf(w0, wp) < wh;
                    int dest = pair * 2 + s;
                    if (bA) adest[nA++] = dest;
                    else if (bB) bdest[nB++] = dest;
                    // neither: result is w0, recomputed in combine — no item
                }
            }
        }
    }
    int lane = threadIdx.x & 63;
    unsigned long long lower = (1ULL << lane) - 1ULL;

    unsigned long long q1 = __ballot(nB >= 1);
    unsigned long long q2 = __ballot(nB == 2);
    int prefB = __popcll(q1 & lower) + __popcll(q2 & lower);
    int totB = __popcll(q1) + __popcll(q2);
    int baseB = 0;
    if (lane == 0 && totB) baseB = atomicAdd(&counters[0], totB);
    baseB = __shfl(baseB, 0, 64);
    if (nB >= 1) queue[baseB + prefB] = bdest[0];
    if (nB == 2) queue[baseB + prefB + 1] = bdest[1];

    unsigned long long p1 = __ballot(nA >= 1);
    unsigned long long p2 = __ballot(nA == 2);
    int prefA = __popcll(p1 & lower) + __popcll(p2 & lower);
    int totA = __popcll(p1) + __popcll(p2);
    int baseA = 0;
    if (lane == 0 && totA) baseA = atomicAdd(&counters[1], totA);
    baseA = __shfl(baseA, 0, 64);
    if (nA >= 1) queue[MAX_ITEMS - 1 - (baseA + prefA)] = adest[0];
    if (nA == 2) queue[MAX_ITEMS - 1 - (baseA + prefA + 1)] = adest[1];
}

// ---------------------------------------------------------------------------
// Kernel 2: process compacted solve items, all lanes active.
// ---------------------------------------------------------------------------
__global__ __launch_bounds__(256)
void solve_kernel(const float* __restrict__ pred,
                  const float* __restrict__ target,
                  const float* __restrict__ crop,
                  const float* __restrict__ prop,
                  const int* __restrict__ cases,
                  const int* __restrict__ counters,
                  const int* __restrict__ queue,
                  float* __restrict__ res) {
#pragma clang fp contract(off)
    int t = blockIdx.x * blockDim.x + threadIdx.x;
    int cntB = counters[0];
    int cntA = counters[1];
    bool isB = t < cntB;
    bool isA = (!isB) && (t >= MAX_ITEMS - cntA);
    if (!isB && !isA) return;
    int dest = queue[t];
    int pair = dest >> 1, slot = dest & 1;
    PairP P = load_pair(pred, target, crop, prop, cases, pair);
    float wp, wh, w0;
    item_params(P, slot, wp, wh, w0);
    float lwp = safe_log_f(wp);
    float r;
    if (isA) {
        r = find_min_e(fmaxf(w0, wh), wp, wh, lwp);  // branchA -> cA
    } else {
        r = solve_B(wp, wh, w0, lwp);  // branchB -> wB
    }
    res[dest] = r;
}

// ---------------------------------------------------------------------------
// Kernel 3: combine. Recomputes the classification predicates (bit-identical)
// to know whether each sub-solve's answer is w0 or res[].
// ---------------------------------------------------------------------------
__device__ __forceinline__ float resolve_s(const float* __restrict__ res,
                                           int pair, int slot, float wp,
                                           float wh, float w0) {
    bool bA = fmaxf(w0, wh) < wp;
    bool bB = fmaxf(w0, wp) < wh;
    return (bA || bB) ? res[pair * 2 + slot] : w0;
}

__global__ __launch_bounds__(256)
void combine_kernel(const float* __restrict__ pred,
                    const float* __restrict__ target,
                    const float* __restrict__ crop,
                    const float* __restrict__ prop,
                    const int* __restrict__ cases,
                    const float* __restrict__ res,
                    float* __restrict__ out) {
#pragma clang fp contract(off)
    int pair = blockIdx.x * blockDim.x + threadIdx.x;
    if (pair >= N_PAIRS) return;
    int row = pair >> 1, axis = pair & 1;
    int r4 = row * 4;
    PairP P = load_pair(pred, target, crop, prop, cases, pair);
    bool need_b = P.lt && P.rb;
    bool need_l = P.lt && !P.rb;
    bool need_r = !P.lt && P.rb;

    float d_lab, w_lab;
    if (need_b) {
        float wh1 = 2.0f * (P.pd - P.a1l);
        float wh2 = 2.0f * (P.b1r - P.pd);
        bool trivial = P.pd >= fmaxf(wh1, wh2);
        if (trivial) {
            d_lab = P.pd;
            w_lab = P.pd;
        } else {
            float w0 = P.b1r - P.a1l;
            float s1 = resolve_s(res, pair, 0, P.pd, wh1, w0);
            float s2 = resolve_s(res, pair, 1, P.pd, wh2, w0);
            float lwp = safe_log_f(P.pd);
            bool pick1 = eps_f(s1, wh1, lwp) <= eps_f(s2, wh2, lwp);
            d_lab = pick1 ? (P.a1l + 0.5f * s1) : (P.b1r + 0.5f * s2);
            w_lab = pick1 ? s1 : s2;
        }
    } else if (need_l) {
        float wh = 2.0f * (P.b1l - P.pd);
        float w0 = P.b1l - P.a1l;
        float s = resolve_s(res, pair, 0, P.po, wh, w0);
        d_lab = P.b1l - 0.5f * s;
        w_lab = s;
    } else if (need_r) {
        float wh = 2.0f * (P.pd - P.a1r);
        float w0 = P.b1r - P.a1r;
        float s = resolve_s(res, pair, 0, P.po, wh, w0);
        d_lab = P.a1r + 0.5f * s;
        w_lab = s;
    } else {
        d_lab = P.td;
        w_lab = P.to;
    }

    out[r4 + axis] = d_lab;
    out[r4 + 2 + axis] = w_lab;
}

extern "C" void kernel_launch(void* const* d_in, const int* in_sizes, int n_in,
                              void* d_out, int out_size, void* d_ws, size_t ws_size,
                              hipStream_t stream) {
    // Inputs: img, pred, target, crop_shapes, proposal_list, cases, sampling_results
    const float* pred = (const float*)d_in[1];
    const float* target = (const float*)d_in[2];
    const float* crop = (const float*)d_in[3];
    const float* prop = (const float*)d_in[4];
    const int* cases = (const int*)d_in[5];
    float* out = (float*)d_out;

    // Workspace layout: [0,8) counters (B,A); [256, 256+2MB) queue ints;
    // [256+2MB, 256+4MB) res floats. Total ~4.2 MB.
    char* ws = (char*)d_ws;
    int* counters = (int*)ws;
    int* queue = (int*)(ws + 256);
    float* res = (float*)(ws + 256 + (size_t)MAX_ITEMS * sizeof(int));

    hipMemsetAsync(counters, 0, 2 * sizeof(int), stream);

    int block = 256;
    classify_kernel<<<N_PAIRS / block, block, 0, stream>>>(
        pred, target, crop, prop, cases, counters, queue);
    solve_kernel<<<MAX_ITEMS / block, block, 0, stream>>>(
        pred, target, crop, prop, cases, counters, queue, res);
    combine_kernel<<<N_PAIRS / block, block, 0, stream>>>(
        pred, target, crop, prop, cases, res, out);
}

// Round 6
// 93.928 us; speedup vs baseline: 1.7803x; 1.7803x over previous
//
#include <hip/hip_runtime.h>
#include <math.h>

#define BISECT_ITERS 60
#define N_ROWS 131072
#define N_PAIRS (2 * N_ROWS)
#define BLOCK 512
#define NW (BLOCK / 64)

// float-rounded versions of python doubles (match numpy scalar->f32 cast)
#define E_CONST 2.71828182845904523536f       // float(np.e)
#define SMALL_THRESH 5.65685424949238019520f  // 4*sqrt(2)
#define LN2F 0.69314718055994530942f

// ---------------------------------------------------------------------------
// Correctly-rounded fp32 natural log (double atanh-series, round once).
// Decision-point path — gave absmax 0.0 vs numpy in round 3. Do not touch.
// ---------------------------------------------------------------------------
__device__ __forceinline__ float log_cr(float wc) {
    double d = (double)wc;
    long long b = __double_as_longlong(d);
    int e = (int)((b >> 52) & 0x7FF) - 1023;
    double m = __longlong_as_double((b & 0x000FFFFFFFFFFFFFLL) |
                                    0x3FF0000000000000LL);  // m in [1,2)
    if (m > 1.3333333333333333) {
        m *= 0.5;
        e += 1;
    }
    double s = (m - 1.0) / (m + 1.0);
    double s2 = s * s;
    double p = 1.0 / 17.0;
    p = fma(p, s2, 1.0 / 15.0);
    p = fma(p, s2, 1.0 / 13.0);
    p = fma(p, s2, 1.0 / 11.0);
    p = fma(p, s2, 1.0 / 9.0);
    p = fma(p, s2, 1.0 / 7.0);
    p = fma(p, s2, 1.0 / 5.0);
    p = fma(p, s2, 1.0 / 3.0);
    p = fma(p, s2, 1.0);
    double res = fma(2.0 * s, p, (double)e * 0.69314718055994530941723212145818);
    return (float)res;
}

__device__ __forceinline__ float safe_log_f(float w) {
    return log_cr(fmaxf(w, 1e-12f));
}

__device__ __forceinline__ float clip1f(float x) {
#pragma clang fp contract(off)
    return fminf(fmaxf(x, -1.0f), 1.0f);
}

__device__ __forceinline__ float sl1(float x) {  // smooth_l1, beta=1
#pragma clang fp contract(off)
    float d = fabsf(x);
    return (d < 1.0f) ? (0.5f * d) * d : d - 0.5f;
}

__device__ __forceinline__ float eps_f(float w, float wh, float lwp) {
#pragma clang fp contract(off)
    return sl1((w - wh) * 0.5f) + sl1(safe_log_f(w) - lwp);
}

__device__ __forceinline__ float eps_prime_cr(float w, float wh, float lwp) {
#pragma clang fp contract(off)
    float x = (w - wh) * 0.5f;
    float diff = safe_log_f(w) - lwp;
    return 0.5f * clip1f(x) + clip1f(diff) / fmaxf(w, 1e-12f);
}

__device__ __forceinline__ float sigma_cr(float w, float wh, float lwp) {
#pragma clang fp contract(off)
    return w * eps_prime_cr(w, wh, lwp);
}

// Fast inner-loop sign of eps_prime (multiplied through by max(m,1e-12)>0).
__device__ __forceinline__ float epsp_sign(float m, float wh, float lwp) {
    float wm = fmaxf(m, 1e-12f);
    float x = (m - wh) * 0.5f;
    float diff = __builtin_fmaf(LN2F, __builtin_amdgcn_logf(wm), -lwp);
    return __builtin_fmaf(0.5f * clip1f(x), wm, clip1f(diff));
}

// ---------- _find_min with f = eps_prime (A-path; round-4 verified) ----------
__device__ float find_min_e(float u, float v, float wh, float lwp) {
#pragma clang fp contract(off)
    float u0 = u, v0 = v;
#pragma unroll 1
    for (int i = 0; i < BISECT_ITERS; ++i) {
        float m = (u + v) * 0.5f;
        bool frozen = (m == u) || (m == v);
        bool c = epsp_sign(m, wh, lwp) >= 0.0f;
        u = c ? u : m;
        v = c ? m : v;
        if (__all(frozen)) break;
    }
    float m = (u + v) * 0.5f;
    float r = m;
    if (eps_prime_cr(v0, wh, lwp) <= 0.0f) r = v0;
    if (eps_prime_cr(u0, wh, lwp) >= 0.0f) r = u0;
    return r;
}

// ---------------------------------------------------------------------------
// Per-pair parameters (fp32 IEEE, contract off — numpy bit-order)
// ---------------------------------------------------------------------------
struct PairP {
    float pd, po, td, to, a1r, b1r, a1l, b1l;
    int lt, rb;
};

__device__ __forceinline__ PairP load_pair(const float* __restrict__ pred,
                                           const float* __restrict__ target,
                                           const float* __restrict__ crop,
                                           const float* __restrict__ prop,
                                           const int* __restrict__ cases,
                                           int pair) {
#pragma clang fp contract(off)
    int row = pair >> 1, axis = pair & 1;
    int d_id = axis, o_id = axis + 2, r4 = row * 4;
    PairP P;
    P.pd = pred[r4 + d_id];
    P.po = (float)exp((double)pred[r4 + o_id]);
    P.td = target[r4 + d_id];
    P.to = (float)exp((double)target[r4 + o_id]);
    float p_d = prop[r4 + d_id];
    float p_o = prop[r4 + o_id];
    float ca = 0.5f * (p_d + p_o);
    float da = p_o - p_d;
    float crop_a = crop[r4 + axis];
    P.a1r = P.td - 0.5f * P.to;
    P.b1r = (crop_a - ca) / da;
    P.a1l = (-ca) / da;
    P.b1l = P.td + 0.5f * P.to;
    P.lt = cases[r4 + 2 * axis];
    P.rb = cases[r4 + 2 * axis + 1];
    return P;
}

// ---------------------------------------------------------------------------
// branchB solve, LARGE variant (wh > 4*sqrt(2)): fuse c2,c3,c5,c6.
// evals[4] is invalid (1e30) per reference's ~small mask — c4 never computed.
// Idempotent-after-freeze updates => bit-exact vs 60 iterations.
// ---------------------------------------------------------------------------
__device__ float solve_B_large(float wp, float wh, float w0, float lwp) {
#pragma clang fp contract(off)
    float ewp = E_CONST * wp;
    float base = fmaxf(w0, fmaxf(wh - 2.0f, ewp));
    float disc = sqrtf(fmaxf(1.0f - 32.0f / fmaxf(wh * wh, 1e-12f), 0.0f));

    float u2 = fmaxf(w0, wp), v2 = fminf(ewp, wh);
    float u3 = fmaxf(fmaxf(w0, 2.0f), fmaxf(wh - 2.0f, ewp)), v3 = wh;
    float u5 = base, v5 = fminf(fminf(ewp, wh), (wh * 0.25f) * (1.0f + disc));
    float u6 = fmaxf(base, (wh * 0.25f) * (1.0f - disc)), v6 = fminf(ewp, wh);
    float u02 = u2, v02 = v2, u03 = u3, v03 = v3;
    float u05 = u5, v05 = v5, u06 = u6, v06 = v6;

#pragma unroll 1
    for (int i = 0; i < BISECT_ITERS; ++i) {
        float m2 = (u2 + v2) * 0.5f;
        float m3 = (u3 + v3) * 0.5f;
        float m5 = (u5 + v5) * 0.5f;
        float m6 = (u6 + v6) * 0.5f;
        bool fr = (m2 == u2 || m2 == v2) && (m3 == u3 || m3 == v3) &&
                  (m5 == u5 || m5 == v5) && (m6 == u6 || m6 == v6);
        bool c2 = epsp_sign(m2, wh, lwp) >= 0.0f;
        bool c3 = epsp_sign(m3, wh, lwp) >= 0.0f;
        bool c5 = (m5 * epsp_sign(m5, wh, lwp)) >= 0.0f;
        bool c6 = (m6 * epsp_sign(m6, wh, lwp)) >= 0.0f;
        u2 = c2 ? u2 : m2; v2 = c2 ? m2 : v2;
        u3 = c3 ? u3 : m3; v3 = c3 ? m3 : v3;
        u5 = c5 ? u5 : m5; v5 = c5 ? m5 : v5;
        u6 = c6 ? u6 : m6; v6 = c6 ? m6 : v6;
        if (__all(fr)) break;
    }

    float c2r = (u2 + v2) * 0.5f;
    if (eps_prime_cr(v02, wh, lwp) <= 0.0f) c2r = v02;
    if (eps_prime_cr(u02, wh, lwp) >= 0.0f) c2r = u02;
    float c3r = (u3 + v3) * 0.5f;
    if (eps_prime_cr(v03, wh, lwp) <= 0.0f) c3r = v03;
    if (eps_prime_cr(u03, wh, lwp) >= 0.0f) c3r = u03;
    float c5r = (u5 + v5) * 0.5f;
    if (sigma_cr(v05, wh, lwp) <= 0.0f) c5r = v05;
    if (sigma_cr(u05, wh, lwp) >= 0.0f) c5r = u05;
    float c6r = (u6 + v6) * 0.5f;
    if (sigma_cr(v06, wh, lwp) <= 0.0f) c6r = v06;
    if (sigma_cr(u06, wh, lwp) >= 0.0f) c6r = u06;

    float cands[7] = {w0, wh, c2r, c3r, 0.0f, c5r, c6r};
    float evals[7];
    evals[0] = eps_f(w0, wh, lwp);
    evals[1] = eps_f(wh, wh, lwp);
    evals[2] = eps_f(c2r, wh, lwp);
    evals[3] = eps_f(c3r, wh, lwp);
    evals[4] = 1e30f;  // ~small -> invalid
    evals[5] = eps_f(c5r, wh, lwp);
    evals[6] = eps_f(c6r, wh, lwp);

    float bestv = evals[0];
    float wB = cands[0];
#pragma unroll
    for (int j = 1; j < 7; ++j) {
        if (evals[j] < bestv) {
            bestv = evals[j];
            wB = cands[j];
        }
    }
    return wB;
}

// ---------------------------------------------------------------------------
// branchB solve, SMALL variant (wh <= 4*sqrt(2)): fuse c2,c3,c4.
// evals[5],[6] invalid per reference's small mask — c5,c6 never computed.
// ---------------------------------------------------------------------------
__device__ float solve_B_small(float wp, float wh, float w0, float lwp) {
#pragma clang fp contract(off)
    float ewp = E_CONST * wp;
    float base = fmaxf(w0, fmaxf(wh - 2.0f, ewp));

    float u2 = fmaxf(w0, wp), v2 = fminf(ewp, wh);
    float u3 = fmaxf(fmaxf(w0, 2.0f), fmaxf(wh - 2.0f, ewp)), v3 = wh;
    float u4 = base, v4 = fminf(E_CONST, wh);
    float u02 = u2, v02 = v2, u03 = u3, v03 = v3, u04 = u4, v04 = v4;

#pragma unroll 1
    for (int i = 0; i < BISECT_ITERS; ++i) {
        float m2 = (u2 + v2) * 0.5f;
        float m3 = (u3 + v3) * 0.5f;
        float m4 = (u4 + v4) * 0.5f;
        bool fr = (m2 == u2 || m2 == v2) && (m3 == u3 || m3 == v3) &&
                  (m4 == u4 || m4 == v4);
        bool c2 = epsp_sign(m2, wh, lwp) >= 0.0f;
        bool c3 = epsp_sign(m3, wh, lwp) >= 0.0f;
        bool c4 = (m4 * epsp_sign(m4, wh, lwp)) >= 0.0f;
        u2 = c2 ? u2 : m2; v2 = c2 ? m2 : v2;
        u3 = c3 ? u3 : m3; v3 = c3 ? m3 : v3;
        u4 = c4 ? u4 : m4; v4 = c4 ? m4 : v4;
        if (__all(fr)) break;
    }

    float c2r = (u2 + v2) * 0.5f;
    if (eps_prime_cr(v02, wh, lwp) <= 0.0f) c2r = v02;
    if (eps_prime_cr(u02, wh, lwp) >= 0.0f) c2r = u02;
    float c3r = (u3 + v3) * 0.5f;
    if (eps_prime_cr(v03, wh, lwp) <= 0.0f) c3r = v03;
    if (eps_prime_cr(u03, wh, lwp) >= 0.0f) c3r = u03;
    float c4r = (u4 + v4) * 0.5f;
    if (sigma_cr(v04, wh, lwp) <= 0.0f) c4r = v04;
    if (sigma_cr(u04, wh, lwp) >= 0.0f) c4r = u04;

    float cands[7] = {w0, wh, c2r, c3r, c4r, 0.0f, 0.0f};
    float evals[7];
    evals[0] = eps_f(w0, wh, lwp);
    evals[1] = eps_f(wh, wh, lwp);
    evals[2] = eps_f(c2r, wh, lwp);
    evals[3] = eps_f(c3r, wh, lwp);
    evals[4] = eps_f(c4r, wh, lwp);
    evals[5] = 1e30f;  // small -> invalid
    evals[6] = 1e30f;

    float bestv = evals[0];
    float wB = cands[0];
#pragma unroll
    for (int j = 1; j < 7; ++j) {
        if (evals[j] < bestv) {
            bestv = evals[j];
            wB = cands[j];
        }
    }
    return wB;
}

// ---------------------------------------------------------------------------
// Fused kernel: block-local classify -> LDS queues -> compacted solve ->
// combine. No global atomics, no workspace, one launch.
// ---------------------------------------------------------------------------
__global__ __launch_bounds__(BLOCK)
void cabb_fused_kernel(const float* __restrict__ pred,
                       const float* __restrict__ target,
                       const float* __restrict__ crop,
                       const float* __restrict__ prop,
                       const int* __restrict__ cases,
                       float* __restrict__ out) {
#pragma clang fp contract(off)
    // B queue (large from bottom, small from top), capacity 2*BLOCK covers the
    // ulp-freak case of 2 branchB items in one both-pair.
    __shared__ float qb_wp[2 * BLOCK], qb_wh[2 * BLOCK], qb_w0[2 * BLOCK];
    __shared__ unsigned short qb_code[2 * BLOCK];
    __shared__ float qa_wp[BLOCK], qa_wh[BLOCK], qa_w0[BLOCK];
    __shared__ unsigned short qa_code[BLOCK];
    __shared__ float s_res[2 * BLOCK];
    __shared__ int s_cnt[NW][3];  // per-wave counts: [Blarge, Bsmall, A]
    __shared__ int s_tot[3];      // running totals across push rounds

    int tid = threadIdx.x;
    int wid = tid >> 6;
    int lane = tid & 63;
    unsigned long long lower = (1ULL << lane) - 1ULL;
    int pair = blockIdx.x * BLOCK + tid;

    if (tid < 3) s_tot[tid] = 0;

    PairP P = load_pair(pred, target, crop, prop, cases, pair);

    bool need_b = P.lt && P.rb;
    bool need_l = P.lt && !P.rb;
    bool need_r = !P.lt && P.rb;

    // ---- classify into up to 2 items (type 0=Blarge, 1=Bsmall, 2=A) ----
    int it_type[2] = {-1, -1};
    float it_wp[2], it_wh[2], it_w0[2];
    unsigned short it_code[2];
    int nit = 0;

    if (need_r || need_l) {
        float wp = P.po;
        float wh = need_l ? 2.0f * (P.b1l - P.pd) : 2.0f * (P.pd - P.a1r);
        float w0 = need_l ? (P.b1l - P.a1l) : (P.b1r - P.a1r);
        bool bA = fmaxf(w0, wh) < wp;
        bool bB = fmaxf(w0, wp) < wh;
        if (bA || bB) {
            it_type[0] = bA ? 2 : (wh <= SMALL_THRESH ? 1 : 0);
            it_wp[0] = wp; it_wh[0] = wh; it_w0[0] = w0;
            it_code[0] = (unsigned short)(tid * 2);
            nit = 1;
        }
    } else if (need_b) {
        float wh1 = 2.0f * (P.pd - P.a1l);
        float wh2 = 2.0f * (P.b1r - P.pd);
        bool trivial = P.pd >= fmaxf(wh1, wh2);
        if (!trivial) {
            float w0 = P.b1r - P.a1l;
            for (int s = 0; s < 2; ++s) {
                float wh = s ? wh2 : wh1;
                bool bA = fmaxf(w0, wh) < P.pd;
                bool bB = fmaxf(w0, P.pd) < wh;
                if (bA || bB) {
                    it_type[nit] = bA ? 2 : (wh <= SMALL_THRESH ? 1 : 0);
                    it_wp[nit] = P.pd; it_wh[nit] = wh; it_w0[nit] = w0;
                    it_code[nit] = (unsigned short)(tid * 2 + s);
                    ++nit;
                }
            }
        }
    }

    // ---- push rounds: ballot-prefix per wave, LDS-scan across waves ----
    for (int k = 0; k < 2; ++k) {
        bool is0 = it_type[k] == 0, is1 = it_type[k] == 1, is2 = it_type[k] == 2;
        unsigned long long m0 = __ballot(is0);
        unsigned long long m1 = __ballot(is1);
        unsigned long long m2 = __ballot(is2);
        if (lane == 0) {
            s_cnt[wid][0] = __popcll(m0);
            s_cnt[wid][1] = __popcll(m1);
            s_cnt[wid][2] = __popcll(m2);
        }
        __syncthreads();
        if (it_type[k] >= 0) {
            int t = it_type[k];
            int base = s_tot[t];
            for (int w = 0; w < wid; ++w) base += s_cnt[w][t];
            unsigned long long mm = t == 0 ? m0 : (t == 1 ? m1 : m2);
            int pos = base + __popcll(mm & lower);
            if (t == 0) {
                qb_wp[pos] = it_wp[k]; qb_wh[pos] = it_wh[k];
                qb_w0[pos] = it_w0[k]; qb_code[pos] = it_code[k];
            } else if (t == 1) {
                int p2 = (2 * BLOCK - 1) - pos;
                qb_wp[p2] = it_wp[k]; qb_wh[p2] = it_wh[k];
                qb_w0[p2] = it_w0[k]; qb_code[p2] = it_code[k];
            } else {
                qa_wp[pos] = it_wp[k]; qa_wh[pos] = it_wh[k];
                qa_w0[pos] = it_w0[k]; qa_code[pos] = it_code[k];
            }
        }
        __syncthreads();
        if (tid < 3) {
            int s = 0;
            for (int w = 0; w < NW; ++w) s += s_cnt[w][tid];
            s_tot[tid] += s;
        }
        __syncthreads();
    }

    int nBl = s_tot[0], nBs = s_tot[1], nA = s_tot[2];

    // ---- solve compacted items: contiguous 64-chunks per wave ----
    for (int base = wid * 64; base < nBl; base += BLOCK) {
        int i = base + lane;
        if (i < nBl) {
            float wp = qb_wp[i], wh = qb_wh[i], w0 = qb_w0[i];
            float lwp = safe_log_f(wp);
            s_res[qb_code[i]] = solve_B_large(wp, wh, w0, lwp);
        }
    }
    for (int base = wid * 64; base < nBs; base += BLOCK) {
        int i = base + lane;
        if (i < nBs) {
            int idx = (2 * BLOCK - 1) - i;
            float wp = qb_wp[idx], wh = qb_wh[idx], w0 = qb_w0[idx];
            float lwp = safe_log_f(wp);
            s_res[qb_code[idx]] = solve_B_small(wp, wh, w0, lwp);
        }
    }
    for (int base = wid * 64; base < nA; base += BLOCK) {
        int i = base + lane;
        if (i < nA) {
            float wp = qa_wp[i], wh = qa_wh[i], w0 = qa_w0[i];
            float lwp = safe_log_f(wp);
            s_res[qa_code[i]] = find_min_e(fmaxf(w0, wh), wp, wh, lwp);
        }
    }
    __syncthreads();

    // ---- combine (predicates recomputed bit-identically) ----
    int row = pair >> 1, axis = pair & 1;
    int r4 = row * 4;
    float d_lab, w_lab;
    if (need_b) {
        float wh1 = 2.0f * (P.pd - P.a1l);
        float wh2 = 2.0f * (P.b1r - P.pd);
        bool trivial = P.pd >= fmaxf(wh1, wh2);
        if (trivial) {
            d_lab = P.pd;
            w_lab = P.pd;
        } else {
            float w0 = P.b1r - P.a1l;
            bool q1 = (fmaxf(w0, wh1) < P.pd) || (fmaxf(w0, P.pd) < wh1);
            bool q2 = (fmaxf(w0, wh2) < P.pd) || (fmaxf(w0, P.pd) < wh2);
            float s1 = q1 ? s_res[tid * 2] : w0;
            float s2 = q2 ? s_res[tid * 2 + 1] : w0;
            float lwp = safe_log_f(P.pd);
            bool pick1 = eps_f(s1, wh1, lwp) <= eps_f(s2, wh2, lwp);
            d_lab = pick1 ? (P.a1l + 0.5f * s1) : (P.b1r + 0.5f * s2);
            w_lab = pick1 ? s1 : s2;
        }
    } else if (need_l) {
        float wh = 2.0f * (P.b1l - P.pd);
        float w0 = P.b1l - P.a1l;
        bool q = (fmaxf(w0, wh) < P.po) || (fmaxf(w0, P.po) < wh);
        float s = q ? s_res[tid * 2] : w0;
        d_lab = P.b1l - 0.5f * s;
        w_lab = s;
    } else if (need_r) {
        float wh = 2.0f * (P.pd - P.a1r);
        float w0 = P.b1r - P.a1r;
        bool q = (fmaxf(w0, wh) < P.po) || (fmaxf(w0, P.po) < wh);
        float s = q ? s_res[tid * 2] : w0;
        d_lab = P.a1r + 0.5f * s;
        w_lab = s;
    } else {
        d_lab = P.td;
        w_lab = P.to;
    }

    out[r4 + axis] = d_lab;
    out[r4 + 2 + axis] = w_lab;
}

extern "C" void kernel_launch(void* const* d_in, const int* in_sizes, int n_in,
                              void* d_out, int out_size, void* d_ws, size_t ws_size,
                              hipStream_t stream) {
    // Inputs: img, pred, target, crop_shapes, proposal_list, cases, sampling_results
    const float* pred = (const float*)d_in[1];
    const float* target = (const float*)d_in[2];
    const float* crop = (const float*)d_in[3];
    const float* prop = (const float*)d_in[4];
    const int* cases = (const int*)d_in[5];
    float* out = (float*)d_out;

    cabb_fused_kernel<<<N_PAIRS / BLOCK, BLOCK, 0, stream>>>(
        pred, target, crop, prop, cases, out);
}

// Round 7
// 86.254 us; speedup vs baseline: 1.9387x; 1.0890x over previous
//
#include <hip/hip_runtime.h>
#include <math.h>

#define BISECT_ITERS 60
#define N_ROWS 131072
#define N_PAIRS (2 * N_ROWS)
#define BLOCK 512
#define NW (BLOCK / 64)

// float-rounded versions of python doubles (match numpy scalar->f32 cast)
#define E_CONST 2.71828182845904523536f       // float(np.e)
#define SMALL_THRESH 5.65685424949238019520f  // 4*sqrt(2)
#define LN2F 0.69314718055994530942f
// fp32 nearest of ln(1e-12) — np's safe_log at/below the clamp
#define LOG1EM12 -27.63102111592854820f

// ---------------------------------------------------------------------------
// Correctly-rounded fp32 natural log (double atanh-series, round once).
// Decision-point path — gave absmax 0.0 vs numpy in round 3. Do not touch,
// except the w<=1e-12 constant fold (bit-identical to log_cr(1e-12)).
// ---------------------------------------------------------------------------
__device__ __forceinline__ float log_cr(float wc) {
    double d = (double)wc;
    long long b = __double_as_longlong(d);
    int e = (int)((b >> 52) & 0x7FF) - 1023;
    double m = __longlong_as_double((b & 0x000FFFFFFFFFFFFFLL) |
                                    0x3FF0000000000000LL);  // m in [1,2)
    if (m > 1.3333333333333333) {
        m *= 0.5;
        e += 1;
    }
    double s = (m - 1.0) / (m + 1.0);
    double s2 = s * s;
    double p = 1.0 / 17.0;
    p = fma(p, s2, 1.0 / 15.0);
    p = fma(p, s2, 1.0 / 13.0);
    p = fma(p, s2, 1.0 / 11.0);
    p = fma(p, s2, 1.0 / 9.0);
    p = fma(p, s2, 1.0 / 7.0);
    p = fma(p, s2, 1.0 / 5.0);
    p = fma(p, s2, 1.0 / 3.0);
    p = fma(p, s2, 1.0);
    double res = fma(2.0 * s, p, (double)e * 0.69314718055994530941723212145818);
    return (float)res;
}

__device__ __forceinline__ float safe_log_f(float w) {
    if (w <= 1e-12f) return LOG1EM12;  // == log_cr(1e-12), constant-folded
    return log_cr(w);
}

__device__ __forceinline__ float clip1f(float x) {
#pragma clang fp contract(off)
    return fminf(fmaxf(x, -1.0f), 1.0f);
}

__device__ __forceinline__ float sl1(float x) {  // smooth_l1, beta=1
#pragma clang fp contract(off)
    float d = fabsf(x);
    return (d < 1.0f) ? (0.5f * d) * d : d - 0.5f;
}

// cr eval: numpy op-order, IEEE fp32, no contraction
__device__ __forceinline__ float eps_f(float w, float wh, float lwp) {
#pragma clang fp contract(off)
    return sl1((w - wh) * 0.5f) + sl1(safe_log_f(w) - lwp);
}

__device__ __forceinline__ float eps_prime_cr(float w, float wh, float lwp) {
#pragma clang fp contract(off)
    float x = (w - wh) * 0.5f;
    float diff = safe_log_f(w) - lwp;
    return 0.5f * clip1f(x) + clip1f(diff) / fmaxf(w, 1e-12f);
}

__device__ __forceinline__ float sigma_cr(float w, float wh, float lwp) {
#pragma clang fp contract(off)
    return w * eps_prime_cr(w, wh, lwp);
}

// Fast native-log ln (<=~4e-6 abs err over the w range here)
__device__ __forceinline__ float nlogf(float w) {
    return LN2F * __builtin_amdgcn_logf(fmaxf(w, 1e-12f));
}

// Fast inner-loop sign of eps_prime (multiplied through by max(m,1e-12)>0).
__device__ __forceinline__ float epsp_sign(float m, float wh, float lwp) {
    float wm = fmaxf(m, 1e-12f);
    float x = (m - wh) * 0.5f;
    float diff = __builtin_fmaf(LN2F, __builtin_amdgcn_logf(wm), -lwp);
    return __builtin_fmaf(0.5f * clip1f(x), wm, clip1f(diff));
}

// ---------------------------------------------------------------------------
// Certified fast sign tests. Return +1/-1 when np's fp32 sign is provable
// from the native-log value (error bound ~4e-6 + 2e-7*wm, threshold 5x that);
// 0 => caller must use the cr path.
// ---------------------------------------------------------------------------
__device__ __forceinline__ int fast_epsp_sgn(float x, float wh, float lwp) {
    float wm = fmaxf(x, 1e-12f);
    float F = epsp_sign(x, wh, lwp);  // ~ wm * eps'(x)
    float tau = 2e-5f * (wm + 1.0f);
    if (F > tau) return 1;
    if (F < -tau) return -1;
    return 0;
}

__device__ __forceinline__ int fast_sigma_sgn(float x, float wh, float lwp) {
    float wm = fmaxf(x, 1e-12f);
    float F = epsp_sign(x, wh, lwp);
    float G = x * F;  // ~ wm * sigma(x)
    float tau = fabsf(x) * (2e-5f * (wm + 1.0f));
    if (G > tau) return 1;
    if (G < -tau) return -1;
    return 0;
}

// Fast eval (native log); err <= ~5e-6 + 1.2e-7*|E|
__device__ __forceinline__ float fast_eval(float w, float wh, float lwp) {
#pragma clang fp contract(off)
    return sl1((w - wh) * 0.5f) + sl1(nlogf(w) - lwp);
}

// ---------- _find_min with f = eps_prime (A-path, rare: keep cr ends) ----------
__device__ float find_min_e(float u, float v, float wh, float lwp) {
#pragma clang fp contract(off)
    float u0 = u, v0 = v;
#pragma unroll 1
    for (int i = 0; i < BISECT_ITERS; ++i) {
        float m = (u + v) * 0.5f;
        bool frozen = (m == u) || (m == v);
        bool c = epsp_sign(m, wh, lwp) >= 0.0f;
        u = c ? u : m;
        v = c ? m : v;
        if (__all(frozen)) break;
    }
    float m = (u + v) * 0.5f;
    float r = m;
    if (eps_prime_cr(v0, wh, lwp) <= 0.0f) r = v0;
    if (eps_prime_cr(u0, wh, lwp) >= 0.0f) r = u0;
    return r;
}

// Endpoint override decisions, certified-fast with cr fallback
__device__ __forceinline__ bool ov_e_le(float x, float wh, float lwp) {
    int s = fast_epsp_sgn(x, wh, lwp);
    if (s < 0) return true;
    if (s > 0) return false;
    return eps_prime_cr(x, wh, lwp) <= 0.0f;
}
__device__ __forceinline__ bool ov_e_ge(float x, float wh, float lwp) {
    int s = fast_epsp_sgn(x, wh, lwp);
    if (s > 0) return true;
    if (s < 0) return false;
    return eps_prime_cr(x, wh, lwp) >= 0.0f;
}
__device__ __forceinline__ bool ov_s_le(float x, float wh, float lwp) {
    int s = fast_sigma_sgn(x, wh, lwp);
    if (s < 0) return true;
    if (s > 0) return false;
    return sigma_cr(x, wh, lwp) <= 0.0f;
}
__device__ __forceinline__ bool ov_s_ge(float x, float wh, float lwp) {
    int s = fast_sigma_sgn(x, wh, lwp);
    if (s > 0) return true;
    if (s < 0) return false;
    return sigma_cr(x, wh, lwp) >= 0.0f;
}

// Certified argmin over 7 candidate/eval slots (1e30 marks invalid).
// Fast first-min; if any other candidate's eval is within the error band AND
// its VALUE differs materially, redo evals with the cr path (np-exact).
__device__ __forceinline__ float argmin7(const float* cands, const float* Ef,
                                         const bool* valid, float wh, float lwp) {
#pragma clang fp contract(off)
    int j = 0;
    float best = Ef[0];
#pragma unroll
    for (int k = 1; k < 7; ++k) {
        if (Ef[k] < best) { best = Ef[k]; j = k; }
    }
    bool need_cr = false;
#pragma unroll
    for (int k = 0; k < 7; ++k) {
        if (k == j) continue;
        float dl = 2e-5f + 2e-6f * (fabsf(best) + fabsf(Ef[k]));
        if (Ef[k] < best + dl &&
            fabsf(cands[k] - cands[j]) > 1e-4f * (1.0f + fabsf(cands[j])))
            need_cr = true;
    }
    if (need_cr) {
        float Ec[7];
#pragma unroll
        for (int k = 0; k < 7; ++k)
            Ec[k] = valid[k] ? eps_f(cands[k], wh, lwp) : 1e30f;
        j = 0;
        best = Ec[0];
#pragma unroll
        for (int k = 1; k < 7; ++k) {
            if (Ec[k] < best) { best = Ec[k]; j = k; }
        }
    }
    return cands[j];
}

// ---------------------------------------------------------------------------
// Per-pair parameters (fp32 IEEE, contract off — numpy bit-order)
// ---------------------------------------------------------------------------
struct PairP {
    float pd, po, td, to, a1r, b1r, a1l, b1l;
    int lt, rb;
};

__device__ __forceinline__ PairP load_pair(const float* __restrict__ pred,
                                           const float* __restrict__ target,
                                           const float* __restrict__ crop,
                                           const float* __restrict__ prop,
                                           const int* __restrict__ cases,
                                           int pair) {
#pragma clang fp contract(off)
    int row = pair >> 1, axis = pair & 1;
    int d_id = axis, o_id = axis + 2, r4 = row * 4;
    PairP P;
    P.pd = pred[r4 + d_id];
    P.po = (float)exp((double)pred[r4 + o_id]);
    P.td = target[r4 + d_id];
    P.to = (float)exp((double)target[r4 + o_id]);
    float p_d = prop[r4 + d_id];
    float p_o = prop[r4 + o_id];
    float ca = 0.5f * (p_d + p_o);
    float da = p_o - p_d;
    float crop_a = crop[r4 + axis];
    P.a1r = P.td - 0.5f * P.to;
    P.b1r = (crop_a - ca) / da;
    P.a1l = (-ca) / da;
    P.b1l = P.td + 0.5f * P.to;
    P.lt = cases[r4 + 2 * axis];
    P.rb = cases[r4 + 2 * axis + 1];
    return P;
}

// ---------------------------------------------------------------------------
// branchB solve, LARGE variant (wh > 4*sqrt(2)): fuse c2,c3,c5,c6.
// ---------------------------------------------------------------------------
__device__ float solve_B_large(float wp, float wh, float w0, float lwp) {
#pragma clang fp contract(off)
    float ewp = E_CONST * wp;
    float base = fmaxf(w0, fmaxf(wh - 2.0f, ewp));
    float disc = sqrtf(fmaxf(1.0f - 32.0f / fmaxf(wh * wh, 1e-12f), 0.0f));

    float u2 = fmaxf(w0, wp), v2 = fminf(ewp, wh);
    float u3 = fmaxf(fmaxf(w0, 2.0f), fmaxf(wh - 2.0f, ewp)), v3 = wh;
    float u5 = base, v5 = fminf(fminf(ewp, wh), (wh * 0.25f) * (1.0f + disc));
    float u6 = fmaxf(base, (wh * 0.25f) * (1.0f - disc)), v6 = fminf(ewp, wh);
    float u02 = u2, v02 = v2, u03 = u3, v03 = v3;
    float u05 = u5, v05 = v5, u06 = u6, v06 = v6;

#pragma unroll 1
    for (int i = 0; i < BISECT_ITERS; ++i) {
        float m2 = (u2 + v2) * 0.5f;
        float m3 = (u3 + v3) * 0.5f;
        float m5 = (u5 + v5) * 0.5f;
        float m6 = (u6 + v6) * 0.5f;
        bool fr = (m2 == u2 || m2 == v2) && (m3 == u3 || m3 == v3) &&
                  (m5 == u5 || m5 == v5) && (m6 == u6 || m6 == v6);
        bool c2 = epsp_sign(m2, wh, lwp) >= 0.0f;
        bool c3 = epsp_sign(m3, wh, lwp) >= 0.0f;
        bool c5 = (m5 * epsp_sign(m5, wh, lwp)) >= 0.0f;
        bool c6 = (m6 * epsp_sign(m6, wh, lwp)) >= 0.0f;
        u2 = c2 ? u2 : m2; v2 = c2 ? m2 : v2;
        u3 = c3 ? u3 : m3; v3 = c3 ? m3 : v3;
        u5 = c5 ? u5 : m5; v5 = c5 ? m5 : v5;
        u6 = c6 ? u6 : m6; v6 = c6 ? m6 : v6;
        if (__all(fr)) break;
    }

    float c2r = (u2 + v2) * 0.5f;
    if (ov_e_le(v02, wh, lwp)) c2r = v02;
    if (ov_e_ge(u02, wh, lwp)) c2r = u02;
    float c3r = (u3 + v3) * 0.5f;
    if (ov_e_le(v03, wh, lwp)) c3r = v03;
    if (ov_e_ge(u03, wh, lwp)) c3r = u03;
    float c5r = (u5 + v5) * 0.5f;
    if (ov_s_le(v05, wh, lwp)) c5r = v05;
    if (ov_s_ge(u05, wh, lwp)) c5r = u05;
    float c6r = (u6 + v6) * 0.5f;
    if (ov_s_le(v06, wh, lwp)) c6r = v06;
    if (ov_s_ge(u06, wh, lwp)) c6r = u06;

    float cands[7] = {w0, wh, c2r, c3r, 0.0f, c5r, c6r};
    bool valid[7] = {true, true, true, true, false, true, true};
    float Ef[7];
    Ef[0] = fast_eval(w0, wh, lwp);
    Ef[1] = fast_eval(wh, wh, lwp);
    Ef[2] = fast_eval(c2r, wh, lwp);
    Ef[3] = fast_eval(c3r, wh, lwp);
    Ef[4] = 1e30f;
    Ef[5] = fast_eval(c5r, wh, lwp);
    Ef[6] = fast_eval(c6r, wh, lwp);
    return argmin7(cands, Ef, valid, wh, lwp);
}

// ---------------------------------------------------------------------------
// branchB solve, SMALL variant (wh <= 4*sqrt(2)): fuse c2,c3,c4.
// ---------------------------------------------------------------------------
__device__ float solve_B_small(float wp, float wh, float w0, float lwp) {
#pragma clang fp contract(off)
    float ewp = E_CONST * wp;
    float base = fmaxf(w0, fmaxf(wh - 2.0f, ewp));

    float u2 = fmaxf(w0, wp), v2 = fminf(ewp, wh);
    float u3 = fmaxf(fmaxf(w0, 2.0f), fmaxf(wh - 2.0f, ewp)), v3 = wh;
    float u4 = base, v4 = fminf(E_CONST, wh);
    float u02 = u2, v02 = v2, u03 = u3, v03 = v3, u04 = u4, v04 = v4;

#pragma unroll 1
    for (int i = 0; i < BISECT_ITERS; ++i) {
        float m2 = (u2 + v2) * 0.5f;
        float m3 = (u3 + v3) * 0.5f;
        float m4 = (u4 + v4) * 0.5f;
        bool fr = (m2 == u2 || m2 == v2) && (m3 == u3 || m3 == v3) &&
                  (m4 == u4 || m4 == v4);
        bool c2 = epsp_sign(m2, wh, lwp) >= 0.0f;
        bool c3 = epsp_sign(m3, wh, lwp) >= 0.0f;
        bool c4 = (m4 * epsp_sign(m4, wh, lwp)) >= 0.0f;
        u2 = c2 ? u2 : m2; v2 = c2 ? m2 : v2;
        u3 = c3 ? u3 : m3; v3 = c3 ? m3 : v3;
        u4 = c4 ? u4 : m4; v4 = c4 ? m4 : v4;
        if (__all(fr)) break;
    }

    float c2r = (u2 + v2) * 0.5f;
    if (ov_e_le(v02, wh, lwp)) c2r = v02;
    if (ov_e_ge(u02, wh, lwp)) c2r = u02;
    float c3r = (u3 + v3) * 0.5f;
    if (ov_e_le(v03, wh, lwp)) c3r = v03;
    if (ov_e_ge(u03, wh, lwp)) c3r = u03;
    float c4r = (u4 + v4) * 0.5f;
    if (ov_s_le(v04, wh, lwp)) c4r = v04;
    if (ov_s_ge(u04, wh, lwp)) c4r = u04;

    float cands[7] = {w0, wh, c2r, c3r, c4r, 0.0f, 0.0f};
    bool valid[7] = {true, true, true, true, true, false, false};
    float Ef[7];
    Ef[0] = fast_eval(w0, wh, lwp);
    Ef[1] = fast_eval(wh, wh, lwp);
    Ef[2] = fast_eval(c2r, wh, lwp);
    Ef[3] = fast_eval(c3r, wh, lwp);
    Ef[4] = fast_eval(c4r, wh, lwp);
    Ef[5] = 1e30f;
    Ef[6] = 1e30f;
    return argmin7(cands, Ef, valid, wh, lwp);
}

// ---------------------------------------------------------------------------
// Fused kernel: block-local classify -> LDS queues -> balanced compacted
// solve -> combine. No global atomics, one launch.
// ---------------------------------------------------------------------------
__global__ __launch_bounds__(BLOCK)
void cabb_fused_kernel(const float* __restrict__ pred,
                       const float* __restrict__ target,
                       const float* __restrict__ crop,
                       const float* __restrict__ prop,
                       const int* __restrict__ cases,
                       float* __restrict__ out) {
#pragma clang fp contract(off)
    __shared__ float qb_wp[2 * BLOCK], qb_wh[2 * BLOCK], qb_w0[2 * BLOCK];
    __shared__ unsigned short qb_code[2 * BLOCK];
    __shared__ float qa_wp[BLOCK], qa_wh[BLOCK], qa_w0[BLOCK];
    __shared__ unsigned short qa_code[BLOCK];
    __shared__ float s_res[2 * BLOCK];
    __shared__ int s_cnt[NW][3];  // per-wave counts: [Blarge, Bsmall, A]
    __shared__ int s_tot[3];      // running totals across push rounds

    int tid = threadIdx.x;
    int wid = tid >> 6;
    int lane = tid & 63;
    unsigned long long lower = (1ULL << lane) - 1ULL;
    int pair = blockIdx.x * BLOCK + tid;

    if (tid < 3) s_tot[tid] = 0;

    PairP P = load_pair(pred, target, crop, prop, cases, pair);

    bool need_b = P.lt && P.rb;
    bool need_l = P.lt && !P.rb;
    bool need_r = !P.lt && P.rb;

    // ---- classify into up to 2 items (type 0=Blarge, 1=Bsmall, 2=A) ----
    int it_type[2] = {-1, -1};
    float it_wp[2], it_wh[2], it_w0[2];
    unsigned short it_code[2];
    int nit = 0;

    if (need_r || need_l) {
        float wp = P.po;
        float wh = need_l ? 2.0f * (P.b1l - P.pd) : 2.0f * (P.pd - P.a1r);
        float w0 = need_l ? (P.b1l - P.a1l) : (P.b1r - P.a1r);
        bool bA = fmaxf(w0, wh) < wp;
        bool bB = fmaxf(w0, wp) < wh;
        if (bA || bB) {
            it_type[0] = bA ? 2 : (wh <= SMALL_THRESH ? 1 : 0);
            it_wp[0] = wp; it_wh[0] = wh; it_w0[0] = w0;
            it_code[0] = (unsigned short)(tid * 2);
            nit = 1;
        }
    } else if (need_b) {
        float wh1 = 2.0f * (P.pd - P.a1l);
        float wh2 = 2.0f * (P.b1r - P.pd);
        bool trivial = P.pd >= fmaxf(wh1, wh2);
        if (!trivial) {
            float w0 = P.b1r - P.a1l;
            for (int s = 0; s < 2; ++s) {
                float wh = s ? wh2 : wh1;
                bool bA = fmaxf(w0, wh) < P.pd;
                bool bB = fmaxf(w0, P.pd) < wh;
                if (bA || bB) {
                    it_type[nit] = bA ? 2 : (wh <= SMALL_THRESH ? 1 : 0);
                    it_wp[nit] = P.pd; it_wh[nit] = wh; it_w0[nit] = w0;
                    it_code[nit] = (unsigned short)(tid * 2 + s);
                    ++nit;
                }
            }
        }
    }

    // ---- push rounds: ballot-prefix per wave, LDS-scan across waves ----
    for (int k = 0; k < 2; ++k) {
        bool is0 = it_type[k] == 0, is1 = it_type[k] == 1, is2 = it_type[k] == 2;
        unsigned long long m0 = __ballot(is0);
        unsigned long long m1 = __ballot(is1);
        unsigned long long m2 = __ballot(is2);
        if (lane == 0) {
            s_cnt[wid][0] = __popcll(m0);
            s_cnt[wid][1] = __popcll(m1);
            s_cnt[wid][2] = __popcll(m2);
        }
        __syncthreads();
        if (it_type[k] >= 0) {
            int t = it_type[k];
            int base = s_tot[t];
            for (int w = 0; w < wid; ++w) base += s_cnt[w][t];
            unsigned long long mm = t == 0 ? m0 : (t == 1 ? m1 : m2);
            int pos = base + __popcll(mm & lower);
            if (t == 0) {
                qb_wp[pos] = it_wp[k]; qb_wh[pos] = it_wh[k];
                qb_w0[pos] = it_w0[k]; qb_code[pos] = it_code[k];
            } else if (t == 1) {
                int p2 = (2 * BLOCK - 1) - pos;
                qb_wp[p2] = it_wp[k]; qb_wh[p2] = it_wh[k];
                qb_w0[p2] = it_w0[k]; qb_code[p2] = it_code[k];
            } else {
                qa_wp[pos] = it_wp[k]; qa_wh[pos] = it_wh[k];
                qa_w0[pos] = it_w0[k]; qa_code[pos] = it_code[k];
            }
        }
        __syncthreads();
        if (tid < 3) {
            int s = 0;
            for (int w = 0; w < NW; ++w) s += s_cnt[w][tid];
            s_tot[tid] += s;
        }
        __syncthreads();
    }

    int nBl = s_tot[0], nBs = s_tot[1], nA = s_tot[2];

    // ---- solve compacted items: round-robin chunk->wave (load balance) ----
    int nBlC = (nBl + 63) >> 6;
    int nBsC = (nBs + 63) >> 6;
    int nAC = (nA + 63) >> 6;
    int totC = nBlC + nBsC + nAC;
    for (int c = wid; c < totC; c += NW) {
        if (c < nBlC) {
            int i = (c << 6) + lane;
            if (i < nBl) {
                float wp = qb_wp[i], wh = qb_wh[i], w0 = qb_w0[i];
                float lwp = safe_log_f(wp);
                s_res[qb_code[i]] = solve_B_large(wp, wh, w0, lwp);
            }
        } else if (c < nBlC + nBsC) {
            int i = ((c - nBlC) << 6) + lane;
            if (i < nBs) {
                int idx = (2 * BLOCK - 1) - i;
                float wp = qb_wp[idx], wh = qb_wh[idx], w0 = qb_w0[idx];
                float lwp = safe_log_f(wp);
                s_res[qb_code[idx]] = solve_B_small(wp, wh, w0, lwp);
            }
        } else {
            int i = ((c - nBlC - nBsC) << 6) + lane;
            if (i < nA) {
                float wp = qa_wp[i], wh = qa_wh[i], w0 = qa_w0[i];
                float lwp = safe_log_f(wp);
                s_res[qa_code[i]] = find_min_e(fmaxf(w0, wh), wp, wh, lwp);
            }
        }
    }
    __syncthreads();

    // ---- combine (predicates recomputed bit-identically) ----
    int row = pair >> 1, axis = pair & 1;
    int r4 = row * 4;
    float d_lab, w_lab;
    if (need_b) {
        float wh1 = 2.0f * (P.pd - P.a1l);
        float wh2 = 2.0f * (P.b1r - P.pd);
        bool trivial = P.pd >= fmaxf(wh1, wh2);
        if (trivial) {
            d_lab = P.pd;
            w_lab = P.pd;
        } else {
            float w0 = P.b1r - P.a1l;
            bool q1 = (fmaxf(w0, wh1) < P.pd) || (fmaxf(w0, P.pd) < wh1);
            bool q2 = (fmaxf(w0, wh2) < P.pd) || (fmaxf(w0, P.pd) < wh2);
            float s1 = q1 ? s_res[tid * 2] : w0;
            float s2 = q2 ? s_res[tid * 2 + 1] : w0;
            // pick1: certified fast compare, cr fallback
            float lwpf = nlogf(P.pd);
            float F1 = sl1((s1 - wh1) * 0.5f) + sl1(nlogf(s1) - lwpf);
            float F2 = sl1((s2 - wh2) * 0.5f) + sl1(nlogf(s2) - lwpf);
            float dl = 3e-5f + 2e-6f * (fabsf(F1) + fabsf(F2));
            bool pick1;
            if (F1 <= F2 - dl) {
                pick1 = true;
            } else if (F1 > F2 + dl) {
                pick1 = false;
            } else {
                float lwp = safe_log_f(P.pd);
                pick1 = eps_f(s1, wh1, lwp) <= eps_f(s2, wh2, lwp);
            }
            d_lab = pick1 ? (P.a1l + 0.5f * s1) : (P.b1r + 0.5f * s2);
            w_lab = pick1 ? s1 : s2;
        }
    } else if (need_l) {
        float wh = 2.0f * (P.b1l - P.pd);
        float w0 = P.b1l - P.a1l;
        bool q = (fmaxf(w0, wh) < P.po) || (fmaxf(w0, P.po) < wh);
        float s = q ? s_res[tid * 2] : w0;
        d_lab = P.b1l - 0.5f * s;
        w_lab = s;
    } else if (need_r) {
        float wh = 2.0f * (P.pd - P.a1r);
        float w0 = P.b1r - P.a1r;
        bool q = (fmaxf(w0, wh) < P.po) || (fmaxf(w0, P.po) < wh);
        float s = q ? s_res[tid * 2] : w0;
        d_lab = P.a1r + 0.5f * s;
        w_lab = s;
    } else {
        d_lab = P.td;
        w_lab = P.to;
    }

    out[r4 + axis] = d_lab;
    out[r4 + 2 + axis] = w_lab;
}

extern "C" void kernel_launch(void* const* d_in, const int* in_sizes, int n_in,
                              void* d_out, int out_size, void* d_ws, size_t ws_size,
                              hipStream_t stream) {
    // Inputs: img, pred, target, crop_shapes, proposal_list, cases, sampling_results
    const float* pred = (const float*)d_in[1];
    const float* target = (const float*)d_in[2];
    const float* crop = (const float*)d_in[3];
    const float* prop = (const float*)d_in[4];
    const int* cases = (const int*)d_in[5];
    float* out = (float*)d_out;

    cabb_fused_kernel<<<N_PAIRS / BLOCK, BLOCK, 0, stream>>>(
        pred, target, crop, prop, cases, out);
}

// Round 8
// 85.284 us; speedup vs baseline: 1.9608x; 1.0114x over previous
//
#include <hip/hip_runtime.h>
#include <math.h>

#define BISECT_ITERS 60
#define N_ROWS 131072
#define N_PAIRS (2 * N_ROWS)
#define BLOCK 512
#define NW (BLOCK / 64)

// float-rounded versions of python doubles (match numpy scalar->f32 cast)
#define E_CONST 2.71828182845904523536f       // float(np.e)
#define SMALL_THRESH 5.65685424949238019520f  // 4*sqrt(2)
#define LN2F 0.69314718055994530942f
// fp32 nearest of ln(1e-12) — np's safe_log at/below the clamp
#define LOG1EM12 -27.63102111592854820f

// ---------------------------------------------------------------------------
// Correctly-rounded fp32 natural log (double atanh-series, round once).
// Decision-point fallback path — gave absmax 0.0 vs numpy in round 3.
// ---------------------------------------------------------------------------
__device__ __forceinline__ float log_cr(float wc) {
    double d = (double)wc;
    long long b = __double_as_longlong(d);
    int e = (int)((b >> 52) & 0x7FF) - 1023;
    double m = __longlong_as_double((b & 0x000FFFFFFFFFFFFFLL) |
                                    0x3FF0000000000000LL);  // m in [1,2)
    if (m > 1.3333333333333333) {
        m *= 0.5;
        e += 1;
    }
    double s = (m - 1.0) / (m + 1.0);
    double s2 = s * s;
    double p = 1.0 / 17.0;
    p = fma(p, s2, 1.0 / 15.0);
    p = fma(p, s2, 1.0 / 13.0);
    p = fma(p, s2, 1.0 / 11.0);
    p = fma(p, s2, 1.0 / 9.0);
    p = fma(p, s2, 1.0 / 7.0);
    p = fma(p, s2, 1.0 / 5.0);
    p = fma(p, s2, 1.0 / 3.0);
    p = fma(p, s2, 1.0);
    double res = fma(2.0 * s, p, (double)e * 0.69314718055994530941723212145818);
    return (float)res;
}

__device__ __forceinline__ float safe_log_f(float w) {
    if (w <= 1e-12f) return LOG1EM12;  // == log_cr(1e-12), constant-folded
    return log_cr(w);
}

__device__ __forceinline__ float clip1f(float x) {
#pragma clang fp contract(off)
    return fminf(fmaxf(x, -1.0f), 1.0f);
}

__device__ __forceinline__ float sl1(float x) {  // smooth_l1, beta=1
#pragma clang fp contract(off)
    float d = fabsf(x);
    return (d < 1.0f) ? (0.5f * d) * d : d - 0.5f;
}

// cr eval: numpy op-order, IEEE fp32, no contraction
__device__ __forceinline__ float eps_f(float w, float wh, float lwp) {
#pragma clang fp contract(off)
    return sl1((w - wh) * 0.5f) + sl1(safe_log_f(w) - lwp);
}

__device__ __forceinline__ float eps_prime_cr(float w, float wh, float lwp) {
#pragma clang fp contract(off)
    float x = (w - wh) * 0.5f;
    float diff = safe_log_f(w) - lwp;
    return 0.5f * clip1f(x) + clip1f(diff) / fmaxf(w, 1e-12f);
}

__device__ __forceinline__ float sigma_cr(float w, float wh, float lwp) {
#pragma clang fp contract(off)
    return w * eps_prime_cr(w, wh, lwp);
}

// Fast native-log ln (<=~4e-6 abs err over the w range here)
__device__ __forceinline__ float nlogf(float w) {
    return LN2F * __builtin_amdgcn_logf(fmaxf(w, 1e-12f));
}

// Fast inner-loop sign of eps_prime (multiplied through by max(m,1e-12)>0).
__device__ __forceinline__ float epsp_sign(float m, float wh, float lwp) {
    float wm = fmaxf(m, 1e-12f);
    float x = (m - wh) * 0.5f;
    float diff = __builtin_fmaf(LN2F, __builtin_amdgcn_logf(wm), -lwp);
    return __builtin_fmaf(0.5f * clip1f(x), wm, clip1f(diff));
}

// ---------------------------------------------------------------------------
// Certified fast sign tests (+1/-1 provable, 0 => cr fallback required).
// ---------------------------------------------------------------------------
__device__ __forceinline__ int fast_epsp_sgn(float x, float wh, float lwp) {
    float wm = fmaxf(x, 1e-12f);
    float F = epsp_sign(x, wh, lwp);  // ~ wm * eps'(x)
    float tau = 2e-5f * (wm + 1.0f);
    if (F > tau) return 1;
    if (F < -tau) return -1;
    return 0;
}

__device__ __forceinline__ int fast_sigma_sgn(float x, float wh, float lwp) {
    float wm = fmaxf(x, 1e-12f);
    float F = epsp_sign(x, wh, lwp);
    float G = x * F;  // ~ wm * sigma(x)
    float tau = fabsf(x) * (2e-5f * (wm + 1.0f));
    if (G > tau) return 1;
    if (G < -tau) return -1;
    return 0;
}

// Fast eval (native log); err <= ~5e-6 + 1.2e-7*|E|
__device__ __forceinline__ float fast_eval(float w, float wh, float lwp) {
#pragma clang fp contract(off)
    return sl1((w - wh) * 0.5f) + sl1(nlogf(w) - lwp);
}

// Endpoint override decisions, certified-fast with cr fallback
__device__ __forceinline__ bool ov_e_le(float x, float wh, float lwp) {
    int s = fast_epsp_sgn(x, wh, lwp);
    if (s < 0) return true;
    if (s > 0) return false;
    return eps_prime_cr(x, wh, lwp) <= 0.0f;
}
__device__ __forceinline__ bool ov_e_ge(float x, float wh, float lwp) {
    int s = fast_epsp_sgn(x, wh, lwp);
    if (s > 0) return true;
    if (s < 0) return false;
    return eps_prime_cr(x, wh, lwp) >= 0.0f;
}
__device__ __forceinline__ bool ov_s_le(float x, float wh, float lwp) {
    int s = fast_sigma_sgn(x, wh, lwp);
    if (s < 0) return true;
    if (s > 0) return false;
    return sigma_cr(x, wh, lwp) <= 0.0f;
}
__device__ __forceinline__ bool ov_s_ge(float x, float wh, float lwp) {
    int s = fast_sigma_sgn(x, wh, lwp);
    if (s > 0) return true;
    if (s < 0) return false;
    return sigma_cr(x, wh, lwp) >= 0.0f;
}

// Certified argmin over 7 candidate/eval slots (1e30 marks invalid).
__device__ __forceinline__ float argmin7(const float* cands, const float* Ef,
                                         const bool* valid, float wh, float lwp) {
#pragma clang fp contract(off)
    int j = 0;
    float best = Ef[0];
#pragma unroll
    for (int k = 1; k < 7; ++k) {
        if (Ef[k] < best) { best = Ef[k]; j = k; }
    }
    bool need_cr = false;
#pragma unroll
    for (int k = 0; k < 7; ++k) {
        if (k == j) continue;
        float dl = 2e-5f + 2e-6f * (fabsf(best) + fabsf(Ef[k]));
        if (Ef[k] < best + dl &&
            fabsf(cands[k] - cands[j]) > 1e-4f * (1.0f + fabsf(cands[j])))
            need_cr = true;
    }
    if (need_cr) {
        float Ec[7];
#pragma unroll
        for (int k = 0; k < 7; ++k)
            Ec[k] = valid[k] ? eps_f(cands[k], wh, lwp) : 1e30f;
        j = 0;
        best = Ec[0];
#pragma unroll
        for (int k = 1; k < 7; ++k) {
            if (Ec[k] < best) { best = Ec[k]; j = k; }
        }
    }
    return cands[j];
}

// Convergence test: frozen (np-exact state) OR width below 1e-5 relative.
// eps is stationary at the root: a 1e-5 root shift moves eps by ~1e-10,
// far below every certified decision band; output tolerance is 2.08.
__device__ __forceinline__ bool cvg(float u, float v, float m) {
    return (m == u) || (m == v) ||
           (fabsf(v - u) <= 1e-5f * fmaxf(1.0f, fabsf(m)));
}

// ---------------------------------------------------------------------------
// Per-pair parameters (fp32 IEEE, contract off — numpy bit-order)
// ---------------------------------------------------------------------------
struct PairP {
    float pd, po, td, to, a1r, b1r, a1l, b1l;
    int lt, rb;
};

__device__ __forceinline__ PairP load_pair(const float* __restrict__ pred,
                                           const float* __restrict__ target,
                                           const float* __restrict__ crop,
                                           const float* __restrict__ prop,
                                           const int* __restrict__ cases,
                                           int pair) {
#pragma clang fp contract(off)
    int row = pair >> 1, axis = pair & 1;
    int d_id = axis, o_id = axis + 2, r4 = row * 4;
    PairP P;
    P.pd = pred[r4 + d_id];
    P.po = (float)exp((double)pred[r4 + o_id]);
    P.td = target[r4 + d_id];
    P.to = (float)exp((double)target[r4 + o_id]);
    float p_d = prop[r4 + d_id];
    float p_o = prop[r4 + o_id];
    float ca = 0.5f * (p_d + p_o);
    float da = p_o - p_d;
    float crop_a = crop[r4 + axis];
    P.a1r = P.td - 0.5f * P.to;
    P.b1r = (crop_a - ca) / da;
    P.a1l = (-ca) / da;
    P.b1l = P.td + 0.5f * P.to;
    P.lt = cases[r4 + 2 * axis];
    P.rb = cases[r4 + 2 * axis + 1];
    return P;
}

// ---------------------------------------------------------------------------
// Unified solver: type is per-lane DATA, not control flow.
//   type 0 = branchB large (subs: c2,c3,c5,c6)
//   type 1 = branchB small (subs: c2,c3,c4; c6 slot dummied)
//   type 2 = branchA       (sub:  cA in the s2 slot; others dummied)
// All subs share one fused bisection loop (identical update code); dummy
// subs have u==v and freeze instantly. Brackets are bit-identical to the
// reference's; endpoint overrides / argmin via certified-fast + cr fallback.
// ---------------------------------------------------------------------------
__device__ float solve_unified(int type, float wp, float wh, float w0, float lwp) {
#pragma clang fp contract(off)
    bool isA = (type == 2);
    bool small_ = (type == 1);
    float ewp = E_CONST * wp;
    float base = fmaxf(w0, fmaxf(wh - 2.0f, ewp));
    float disc = sqrtf(fmaxf(1.0f - 32.0f / fmaxf(wh * wh, 1e-12f), 0.0f));

    // s2: eps-prime bisection — B's c2, or A's cA bracket
    float u2 = isA ? fmaxf(w0, wh) : fmaxf(w0, wp);
    float v2 = isA ? wp : fminf(ewp, wh);
    // s3: eps-prime bisection — B's c3 (dummy for A)
    float u3 = fmaxf(fmaxf(w0, 2.0f), fmaxf(wh - 2.0f, ewp));
    float v3 = isA ? u3 : wh;
    // s4: sigma bisection — small's c4 or large's c5 (dummy for A)
    float u4 = base;
    float v4 = isA ? base
                   : (small_ ? fminf(E_CONST, wh)
                             : fminf(fminf(ewp, wh),
                                     (wh * 0.25f) * (1.0f + disc)));
    // s6: sigma bisection — large's c6 (dummy for A/small)
    float u6 = fmaxf(base, (wh * 0.25f) * (1.0f - disc));
    float v6 = (isA || small_) ? u6 : fminf(ewp, wh);

    float u02 = u2, v02 = v2, u03 = u3, v03 = v3;
    float u04 = u4, v04 = v4, u06 = u6, v06 = v6;

#pragma unroll 1
    for (int i = 0; i < BISECT_ITERS; ++i) {
        float m2 = (u2 + v2) * 0.5f;
        float m3 = (u3 + v3) * 0.5f;
        float m4 = (u4 + v4) * 0.5f;
        float m6 = (u6 + v6) * 0.5f;
        bool fr = cvg(u2, v2, m2) && cvg(u3, v3, m3) &&
                  cvg(u4, v4, m4) && cvg(u6, v6, m6);
        bool c2 = epsp_sign(m2, wh, lwp) >= 0.0f;
        bool c3 = epsp_sign(m3, wh, lwp) >= 0.0f;
        bool c4 = (m4 * epsp_sign(m4, wh, lwp)) >= 0.0f;
        bool c6 = (m6 * epsp_sign(m6, wh, lwp)) >= 0.0f;
        u2 = c2 ? u2 : m2; v2 = c2 ? m2 : v2;
        u3 = c3 ? u3 : m3; v3 = c3 ? m3 : v3;
        u4 = c4 ? u4 : m4; v4 = c4 ? m4 : v4;
        u6 = c6 ? u6 : m6; v6 = c6 ? m6 : v6;
        if (__all(fr)) break;
    }

    float r2 = (u2 + v2) * 0.5f;
    if (ov_e_le(v02, wh, lwp)) r2 = v02;
    if (ov_e_ge(u02, wh, lwp)) r2 = u02;
    float r3 = (u3 + v3) * 0.5f;
    if (ov_e_le(v03, wh, lwp)) r3 = v03;
    if (ov_e_ge(u03, wh, lwp)) r3 = u03;
    float r4 = (u4 + v4) * 0.5f;
    if (ov_s_le(v04, wh, lwp)) r4 = v04;
    if (ov_s_ge(u04, wh, lwp)) r4 = u04;
    float r6 = (u6 + v6) * 0.5f;
    if (ov_s_le(v06, wh, lwp)) r6 = v06;
    if (ov_s_ge(u06, wh, lwp)) r6 = u06;

    // slot4 = small's c4, slot5 = large's c5 — same register r4
    float cands[7] = {w0, wh, r2, r3, r4, r4, r6};
    bool valid[7] = {!isA, !isA, !isA, !isA,
                     small_, !isA && !small_, !isA && !small_};
    float Ef[7];
#pragma unroll
    for (int k = 0; k < 7; ++k)
        Ef[k] = valid[k] ? fast_eval(cands[k], wh, lwp) : 1e30f;
    float wB = argmin7(cands, Ef, valid, wh, lwp);
    return isA ? r2 : wB;
}

// ---------------------------------------------------------------------------
// Fused kernel: classify -> single LDS queue (one push round, one chunk
// ceiling) -> unified compacted solve -> combine. 3 barriers total.
// ---------------------------------------------------------------------------
__global__ __launch_bounds__(BLOCK)
void cabb_fused_kernel(const float* __restrict__ pred,
                       const float* __restrict__ target,
                       const float* __restrict__ crop,
                       const float* __restrict__ prop,
                       const int* __restrict__ cases,
                       float* __restrict__ out) {
#pragma clang fp contract(off)
    __shared__ float q_wp[2 * BLOCK], q_wh[2 * BLOCK], q_w0[2 * BLOCK];
    __shared__ unsigned short q_code[2 * BLOCK];  // dest(12b) | type<<12
    __shared__ float s_res[2 * BLOCK];
    __shared__ int s_cnt[NW];

    int tid = threadIdx.x;
    int wid = tid >> 6;
    int lane = tid & 63;
    unsigned long long lower = (1ULL << lane) - 1ULL;
    int pair = blockIdx.x * BLOCK + tid;

    PairP P = load_pair(pred, target, crop, prop, cases, pair);

    bool need_b = P.lt && P.rb;
    bool need_l = P.lt && !P.rb;
    bool need_r = !P.lt && P.rb;

    // ---- classify into up to 2 items (type 0=Blarge, 1=Bsmall, 2=A) ----
    int it_type[2] = {-1, -1};
    float it_wp[2], it_wh[2], it_w0[2];
    unsigned short it_code[2];
    int nit = 0;

    if (need_r || need_l) {
        float wp = P.po;
        float wh = need_l ? 2.0f * (P.b1l - P.pd) : 2.0f * (P.pd - P.a1r);
        float w0 = need_l ? (P.b1l - P.a1l) : (P.b1r - P.a1r);
        bool bA = fmaxf(w0, wh) < wp;
        bool bB = fmaxf(w0, wp) < wh;
        if (bA || bB) {
            it_type[0] = bA ? 2 : (wh <= SMALL_THRESH ? 1 : 0);
            it_wp[0] = wp; it_wh[0] = wh; it_w0[0] = w0;
            it_code[0] = (unsigned short)(tid * 2);
            nit = 1;
        }
    } else if (need_b) {
        float wh1 = 2.0f * (P.pd - P.a1l);
        float wh2 = 2.0f * (P.b1r - P.pd);
        bool trivial = P.pd >= fmaxf(wh1, wh2);
        if (!trivial) {
            float w0 = P.b1r - P.a1l;
            for (int s = 0; s < 2; ++s) {
                float wh = s ? wh2 : wh1;
                bool bA = fmaxf(w0, wh) < P.pd;
                bool bB = fmaxf(w0, P.pd) < wh;
                if (bA || bB) {
                    it_type[nit] = bA ? 2 : (wh <= SMALL_THRESH ? 1 : 0);
                    it_wp[nit] = P.pd; it_wh[nit] = wh; it_w0[nit] = w0;
                    it_code[nit] = (unsigned short)(tid * 2 + s);
                    ++nit;
                }
            }
        }
    }

    // ---- single push round: ballot-prefix per wave, LDS-scan across waves ----
    bool h0 = it_type[0] >= 0;
    bool h1 = it_type[1] >= 0;
    unsigned long long mA = __ballot(h0);
    unsigned long long mB = __ballot(h1);
    int popA = __popcll(mA);
    if (lane == 0) s_cnt[wid] = popA + __popcll(mB);
    __syncthreads();
    int qbase = 0, nQ = 0;
#pragma unroll
    for (int w = 0; w < NW; ++w) {
        int c = s_cnt[w];
        if (w < wid) qbase += c;
        nQ += c;
    }
    if (h0) {
        int p = qbase + __popcll(mA & lower);
        q_wp[p] = it_wp[0]; q_wh[p] = it_wh[0]; q_w0[p] = it_w0[0];
        q_code[p] = (unsigned short)(it_code[0] | (it_type[0] << 12));
    }
    if (h1) {
        int p = qbase + popA + __popcll(mB & lower);
        q_wp[p] = it_wp[1]; q_wh[p] = it_wh[1]; q_w0[p] = it_w0[1];
        q_code[p] = (unsigned short)(it_code[1] | (it_type[1] << 12));
    }
    __syncthreads();

    // ---- unified compacted solve: round-robin chunk->wave ----
    int chunks = (nQ + 63) >> 6;
    for (int c = wid; c < chunks; c += NW) {
        int i = (c << 6) + lane;
        if (i < nQ) {
            float wp = q_wp[i], wh = q_wh[i], w0 = q_w0[i];
            int cc = q_code[i];
            float lwp = safe_log_f(wp);
            s_res[cc & 0xFFF] = solve_unified(cc >> 12, wp, wh, w0, lwp);
        }
    }
    __syncthreads();

    // ---- combine (predicates recomputed bit-identically) ----
    int row = pair >> 1, axis = pair & 1;
    int r4 = row * 4;
    float d_lab, w_lab;
    if (need_b) {
        float wh1 = 2.0f * (P.pd - P.a1l);
        float wh2 = 2.0f * (P.b1r - P.pd);
        bool trivial = P.pd >= fmaxf(wh1, wh2);
        if (trivial) {
            d_lab = P.pd;
            w_lab = P.pd;
        } else {
            float w0 = P.b1r - P.a1l;
            bool q1 = (fmaxf(w0, wh1) < P.pd) || (fmaxf(w0, P.pd) < wh1);
            bool q2 = (fmaxf(w0, wh2) < P.pd) || (fmaxf(w0, P.pd) < wh2);
            float s1 = q1 ? s_res[tid * 2] : w0;
            float s2 = q2 ? s_res[tid * 2 + 1] : w0;
            // pick1: certified fast compare, cr fallback
            float lwpf = nlogf(P.pd);
            float F1 = sl1((s1 - wh1) * 0.5f) + sl1(nlogf(s1) - lwpf);
            float F2 = sl1((s2 - wh2) * 0.5f) + sl1(nlogf(s2) - lwpf);
            float dl = 3e-5f + 2e-6f * (fabsf(F1) + fabsf(F2));
            bool pick1;
            if (F1 <= F2 - dl) {
                pick1 = true;
            } else if (F1 > F2 + dl) {
                pick1 = false;
            } else {
                float lwp = safe_log_f(P.pd);
                pick1 = eps_f(s1, wh1, lwp) <= eps_f(s2, wh2, lwp);
            }
            d_lab = pick1 ? (P.a1l + 0.5f * s1) : (P.b1r + 0.5f * s2);
            w_lab = pick1 ? s1 : s2;
        }
    } else if (need_l) {
        float wh = 2.0f * (P.b1l - P.pd);
        float w0 = P.b1l - P.a1l;
        bool q = (fmaxf(w0, wh) < P.po) || (fmaxf(w0, P.po) < wh);
        float s = q ? s_res[tid * 2] : w0;
        d_lab = P.b1l - 0.5f * s;
        w_lab = s;
    } else if (need_r) {
        float wh = 2.0f * (P.pd - P.a1r);
        float w0 = P.b1r - P.a1r;
        bool q = (fmaxf(w0, wh) < P.po) || (fmaxf(w0, P.po) < wh);
        float s = q ? s_res[tid * 2] : w0;
        d_lab = P.a1r + 0.5f * s;
        w_lab = s;
    } else {
        d_lab = P.td;
        w_lab = P.to;
    }

    out[r4 + axis] = d_lab;
    out[r4 + 2 + axis] = w_lab;
}

extern "C" void kernel_launch(void* const* d_in, const int* in_sizes, int n_in,
                              void* d_out, int out_size, void* d_ws, size_t ws_size,
                              hipStream_t stream) {
    // Inputs: img, pred, target, crop_shapes, proposal_list, cases, sampling_results
    const float* pred = (const float*)d_in[1];
    const float* target = (const float*)d_in[2];
    const float* crop = (const float*)d_in[3];
    const float* prop = (const float*)d_in[4];
    const int* cases = (const int*)d_in[5];
    float* out = (float*)d_out;

    cabb_fused_kernel<<<N_PAIRS / BLOCK, BLOCK, 0, stream>>>(
        pred, target, crop, prop, cases, out);
}